// Round 14
// baseline (137.984 us; speedup 1.0000x reference)
//
#include <hip/hip_runtime.h>

#define Lq 512
#define Bn 1024
#define Tq 48

typedef float f32x4 __attribute__((ext_vector_type(4)));
typedef short s16x8 __attribute__((ext_vector_type(8)));
typedef unsigned u32x4 __attribute__((ext_vector_type(4)));

#define MFMA(a, b, c) __builtin_amdgcn_mfma_f32_16x16x32_bf16((a), (b), (c), 0, 0, 0)

__device__ __forceinline__ unsigned cvtpk(float lo, float hi) {
    unsigned r;
    asm("v_cvt_pk_bf16_f32 %0, %1, %2" : "=v"(r) : "v"(lo), "v"(hi));
    return r;
}
__device__ __forceinline__ short f2b(float x) {       // fp32 -> bf16 bits, RNE
    unsigned u = __float_as_uint(x);
    return (short)((u + 0x7fffu + ((u >> 16) & 1u)) >> 16);
}

// rebuild B fragments from this lane's own pn: kappa-slot permutation makes
// the C layout feed B directly (no LDS, no cross-lane movement). [R11-proven]
#define PACKB do {                                                            \
    unsigned d0_ = cvtpk(pn0[0], pn0[1]), d1_ = cvtpk(pn0[2], pn0[3]);        \
    unsigned d2_ = cvtpk(pn1[0], pn1[1]), d3_ = cvtpk(pn1[2], pn1[3]);        \
    unsigned d4_ = cvtpk(pn2[0], pn2[1]), d5_ = cvtpk(pn2[2], pn2[3]);        \
    u32x4 b0_ = {d0_, d1_, d2_, d3_};                                         \
    u32x4 b1_ = {d4_, d5_, 0u, 0u};                                           \
    Bk0 = __builtin_bit_cast(s16x8, b0_);                                     \
    Bk1 = __builtin_bit_cast(s16x8, b1_);                                     \
} while (0)

// one forward step: C = W^T*P (6 MFMAs), pn = mask ? C*exp(e) : pn,
// optional IMMEDIATE per-column power-of-2 rescale (R9/R11-proven), repack B.
#define STEP(EA, EB, EC, MV, RS) do {                                         \
    f32x4 C0_ = MFMA(aw00, Bk0, Zf); C0_ = MFMA(aw01, Bk1, C0_);              \
    f32x4 C1_ = MFMA(aw10, Bk0, Zf); C1_ = MFMA(aw11, Bk1, C1_);              \
    f32x4 C2_ = MFMA(aw20, Bk0, Zf); C2_ = MFMA(aw21, Bk1, C2_);              \
    pn0[0] = (MV) ? C0_[0] * __expf((EA)[0]) : pn0[0];                        \
    pn0[1] = (MV) ? C0_[1] * __expf((EA)[1]) : pn0[1];                        \
    pn0[2] = (MV) ? C0_[2] * __expf((EA)[2]) : pn0[2];                        \
    pn0[3] = (MV) ? C0_[3] * __expf((EA)[3]) : pn0[3];                        \
    pn1[0] = (MV) ? C1_[0] * __expf((EB)[0]) : pn1[0];                        \
    pn1[1] = (MV) ? C1_[1] * __expf((EB)[1]) : pn1[1];                        \
    pn1[2] = (MV) ? C1_[2] * __expf((EB)[2]) : pn1[2];                        \
    pn1[3] = (MV) ? C1_[3] * __expf((EB)[3]) : pn1[3];                        \
    pn2[0] = (MV) ? C2_[0] * __expf((EC)[0]) : pn2[0];                        \
    pn2[1] = (MV) ? C2_[1] * __expf((EC)[1]) : pn2[1];                        \
    pn2[2] = (MV) ? C2_[2] * __expf((EC)[2]) : pn2[2];                        \
    pn2[3] = (MV) ? C2_[3] * __expf((EC)[3]) : pn2[3];                        \
    if (RS) {                                                                 \
        float rep_ = __shfl(pn0[0], cidx, 64);      /* column c, state 0 */   \
        int k_ = ((__float_as_int(rep_) >> 23) & 0xff) - 126;                 \
        float scl_ = __int_as_float((127 - k_) << 23);  /* 2^-k exact */      \
        pn0[0]*=scl_; pn0[1]*=scl_; pn0[2]*=scl_; pn0[3]*=scl_;               \
        pn1[0]*=scl_; pn1[1]*=scl_; pn1[2]*=scl_; pn1[3]*=scl_;               \
        pn2[0]*=scl_; pn2[1]*=scl_; pn2[2]*=scl_; pn2[3]*=scl_;               \
        c2 += k_;                                                             \
    }                                                                         \
    PACKB;                                                                    \
} while (0)

// refill slot D with step T's raw emissions (3 x dwordx4) + per-column mask
#define LOAD_SLOT(D, T) do {                                                  \
    int t_ = (T); int v_ = (t_ < Lq); int tc_ = v_ ? t_ : (Lq - 1);           \
    const float* ep_ = em + ((size_t)tc_ * Bn + bidx) * Tq;                   \
    ea_##D = *(const f32x4*)(ep_ + 4 * qidx);                                 \
    eb_##D = *(const f32x4*)(ep_ + 16 + 4 * qidx);                            \
    ec_##D = *(const f32x4*)(ep_ + 32 + 4 * qidx);                            \
    m_##D  = v_ ? mask[tc_ * Bn + bidx] : 0;                                  \
} while (0)

// ---------------- Fused kernel ----------------
// blocks 0..63: MFMA forward algorithm (16 batch columns per wave).
// blocks 64..575: numerator (gold-path score), grid-stride.
// __launch_bounds__(64, 1): 1 wave/EU minimum -> full VGPR budget (the R11
// binary capped at 72 VGPRs and spilled the prefetch slots to scratch).
__global__ __launch_bounds__(64, 1) void crf_fused(
    const float* __restrict__ em, const int* __restrict__ tags,
    const int* __restrict__ mask, const float* __restrict__ startT,
    const float* __restrict__ endT, const float* __restrict__ trans,
    float* __restrict__ out)
{
    const int j = threadIdx.x;
    __shared__ float shf[Tq * Tq];

    if (blockIdx.x < 64) {
        // ---------------- forward path ----------------
        const int cidx = j & 15;          // batch column within wave
        const int qidx = j >> 4;          // k-slot group
        const int bidx = blockIdx.x * 16 + cidx;

        // stage trans, then build W^T A-fragments under the SAME kappa-slot
        // permutation PACKB uses: kb0,i<4 -> 4q+i ; kb0,i>=4 -> 12+4q+i ;
        // kb1,i<4 -> 32+4q+i ; kb1,i>=4 -> zero pad. [R11-proven]
        for (int i = j; i < Tq * Tq; i += 64) shf[i] = trans[i];
        __syncthreads();
        s16x8 aw00, aw01, aw10, aw11, aw20, aw21;
#pragma unroll
        for (int i = 0; i < 8; ++i) {
            int l0 = (i < 4) ? (4 * qidx + i) : (12 + 4 * qidx + i);
            aw00[i] = f2b(__expf(shf[l0 * Tq + cidx]));
            aw10[i] = f2b(__expf(shf[l0 * Tq + 16 + cidx]));
            aw20[i] = f2b(__expf(shf[l0 * Tq + 32 + cidx]));
            if (i < 4) {
                int l1 = 32 + 4 * qidx + i;
                aw01[i] = f2b(__expf(shf[l1 * Tq + cidx]));
                aw11[i] = f2b(__expf(shf[l1 * Tq + 16 + cidx]));
                aw21[i] = f2b(__expf(shf[l1 * Tq + 32 + cidx]));
            } else {
                aw01[i] = 0; aw11[i] = 0; aw21[i] = 0;
            }
        }

        // P_0 (C layout, identity state map): pn_n[i] = exp(start+em0), s=16n+4q+i
        f32x4 pn0, pn1, pn2;
        {
            const float* e0p = em + (size_t)bidx * Tq;
            f32x4 ea = *(const f32x4*)(e0p + 4 * qidx);
            f32x4 eb = *(const f32x4*)(e0p + 16 + 4 * qidx);
            f32x4 ec = *(const f32x4*)(e0p + 32 + 4 * qidx);
#pragma unroll
            for (int i = 0; i < 4; ++i) {
                pn0[i] = __expf(startT[ 0 + 4 * qidx + i] + ea[i]);
                pn1[i] = __expf(startT[16 + 4 * qidx + i] + eb[i]);
                pn2[i] = __expf(startT[32 + 4 * qidx + i] + ec[i]);
            }
        }

        const f32x4 Zf = {0.f, 0.f, 0.f, 0.f};
        s16x8 Bk0, Bk1;
        int c2 = 0;
        PACKB;

        // 4 prefetch slots, named scalars (R11-proven lead of 4 steps)
        f32x4 ea_0, eb_0, ec_0, ea_1, eb_1, ec_1;
        f32x4 ea_2, eb_2, ec_2, ea_3, eb_3, ec_3;
        int m_0, m_1, m_2, m_3;
        LOAD_SLOT(0, 1); LOAD_SLOT(1, 2); LOAD_SLOT(2, 3); LOAD_SLOT(3, 4);

        // 128 chunks x 4 steps cover t = 1..512 (t=512 is a masked no-op);
        // immediate rescale at every 4th step (R9/R11-proven).
        for (int ch = 0; ch < 128; ++ch) {
            const int tb = 1 + 4 * ch;
            STEP(ea_0, eb_0, ec_0, m_0, 0); LOAD_SLOT(0, tb + 4);
            STEP(ea_1, eb_1, ec_1, m_1, 0); LOAD_SLOT(1, tb + 5);
            STEP(ea_2, eb_2, ec_2, m_2, 0); LOAD_SLOT(2, tb + 6);
            STEP(ea_3, eb_3, ec_3, m_3, 1); LOAD_SLOT(3, tb + 7);
        }

        // z_c = sum_s P[s][c]*exp(end[s]); states at this lane: 16n+4q+i
        float zacc = 0.f;
#pragma unroll
        for (int i = 0; i < 4; ++i) {
            zacc += pn0[i] * __expf(endT[ 0 + 4 * qidx + i]);
            zacc += pn1[i] * __expf(endT[16 + 4 * qidx + i]);
            zacc += pn2[i] * __expf(endT[32 + 4 * qidx + i]);
        }
        zacc += __shfl_xor(zacc, 16, 64);
        zacc += __shfl_xor(zacc, 32, 64);
        float nl = -(__logf(zacc) + (float)c2 * 0.6931471805599453f);
        nl += __shfl_xor(nl, 1, 64);
        nl += __shfl_xor(nl, 2, 64);
        nl += __shfl_xor(nl, 4, 64);
        nl += __shfl_xor(nl, 8, 64);
        if (j == 0) atomicAdd(out, nl);
    } else {
        // ---------------- numerator path ----------------
        const int bid = blockIdx.x - 64;          // 0..511
        float c = 0.0f;
        for (int id = bid * 64 + j; id < Lq * Bn; id += 512 * 64) {
            int t  = id >> 10;
            int bb = id & (Bn - 1);
            int tag = tags[id];
            int m_t = mask[id];
            if (t == 0) c += startT[tag];
            bool is_last;
            if (t < Lq - 1) {
                if (m_t) c += em[(size_t)id * Tq + tag];
                int tag1 = tags[id + Bn];
                int m1   = mask[id + Bn];
                if (m1) c += trans[tag * Tq + tag1];
                is_last = (m_t != 0) && (m1 == 0);
            } else {
                is_last = (m_t != 0);
            }
            if (is_last) {
                c += endT[tag];
                int mL = mask[(Lq - 1) * Bn + bb];
                if (mL) c += em[((size_t)(Lq - 1) * Bn + bb) * Tq + tag];
            }
        }
#pragma unroll
        for (int off = 32; off >= 1; off >>= 1)
            c += __shfl_xor(c, off, 64);
        if (j == 0) atomicAdd(out, c);
    }
}

extern "C" void kernel_launch(void* const* d_in, const int* in_sizes, int n_in,
                              void* d_out, int out_size, void* d_ws, size_t ws_size,
                              hipStream_t stream) {
    const float* em     = (const float*)d_in[0];
    const int*   tags   = (const int*)d_in[1];
    const int*   mask   = (const int*)d_in[2];
    const float* startT = (const float*)d_in[3];
    const float* endT   = (const float*)d_in[4];
    const float* trans  = (const float*)d_in[5];
    float* out = (float*)d_out;

    hipMemsetAsync(out, 0, sizeof(float), stream);
    crf_fused<<<576, 64, 0, stream>>>(em, tags, mask, startT, endT, trans, out);
}